// Round 10
// baseline (41.597 us; speedup 1.0000x reference)
//
#include <hip/hip_runtime.h>
#include <math.h>

// Affine warp augmentation (kornia-style warp_affine, bilinear, zeros padding,
// align_corners pixel coords). B=128, C=3, H=W=256, fp32.
//
// R10: occupancy fix. R9 pinned at ~41.5us with OccupancyPercent 45% (28.2KB
// LDS -> 5 blocks/CU) and nothing saturated -> latency-bound. TH 64->32:
// row span = (|i10|+i11)*31 <= 62.5 -> MAXROWS 70 -> LDS 17.9 KB -> 8
// blocks/CU = 32 waves = 100% occupancy (wave-capped). Staging redundancy
// 2.0->2.7x is L2-hit traffic (headroom). Everything else carried from R9:
//  - PITCH=64: gather bank = x0%32 -> angle-independent ~conflict-free
//    (R8 proved: 6.46M -> 1.75M conflict cycles); ds_write_b128 staging.
//  - i01 == 0 exactly (a = hx-r = 0) -> sx/x0/wx hoisted out of the y-loop.
//  - Per-(b,tile) bbox precomputed in params kernel; 3D grid (B,nTile,C) ->
//    no divides in hot kernel; gridDim.x=128 = 0 mod 8 pins each image's
//    blocks to one XCD's L2.
//  - float4 zero-halo staging with fast interior path; mask-free bilinear
//    inner loop (zero-halo reproduces zeros-padding exactly).

#define AUG_ANG 0.34906585039886590  // deg2rad(20)
#define AUG_MAX_T 6.0

#define TW 32
#define TH 32
#define PITCH 64       // power-of-2: bank = x0 % 32 (y0 vanishes); b128-aligned
#define MAXROWS 70     // >= (|i10|+i11)*31 + 5 = 62.5 + 5
#define SLOTS 10       // staged float4 slots per row (40 floats >= ws 38)

// One thread per (b, tile): builds the per-b affine params (thread with
// tile==0 writes them) and the per-(b,tile) source bbox.
__global__ void TCR_params_kernel(const float* __restrict__ rnd,
                                  float* __restrict__ p,
                                  int4* __restrict__ bb,
                                  int B, int W, int H,
                                  int tilesX, int nTile) {
    const int idx = blockIdx.x * blockDim.x + threadIdx.x;
    if (idx >= B * nTile) return;
    const int b = idx / nTile;
    const int t = idx - b * nTile;

    double r01 = (double)rnd[b];
    double tx = 2.0 * AUG_MAX_T * r01 - AUG_MAX_T;
    double ty = tx;                       // same random tensor for all params
    double r  = 2.0 * AUG_ANG * r01 - AUG_ANG;
    double z  = 1.0;                      // MAX_Z == MIN_Z == 1
    double hx = r, hy = r;
    double a  = hx - r;                   // == 0 exactly
    double bbang = hy + r;
    double cos_hx = cos(hx), cos_hy = cos(hy);
    double ca = cos(a),  sa = sin(a);
    double cb = cos(bbang), sb = sin(bbang);
    double T11 = z * ca / cos_hx;
    double T12 = z * sa / cos_hx;
    double T13 = ((double)W * cos_hx - (double)W * z * ca + 2.0 * tx * z * ca
                  - (double)H * z * sa + 2.0 * ty * z * sa) / (2.0 * cos_hx);
    double T21 = z * sb / cos_hy;
    double T22 = z * cb / cos_hy;
    double T23 = ((double)H * cos_hy - (double)W * z * cb + 2.0 * ty * z * cb
                  - (double)W * z * sb + 2.0 * tx * z * sb) / (2.0 * cos_hy);
    double det = T11 * T22 - T12 * T21;
    const float i00 = (float)( T22 / det);
    const float i01 = (float)(-T12 / det);   // == +/-0
    const float i10 = (float)(-T21 / det);
    const float i11 = (float)( T11 / det);
    const float f13 = (float)T13;
    const float f23 = (float)T23;

    if (t == 0) {
        p[b * 6 + 0] = i00;
        p[b * 6 + 1] = i01;
        p[b * 6 + 2] = i10;
        p[b * 6 + 3] = i11;
        p[b * 6 + 4] = f13;
        p[b * 6 + 5] = f23;
    }

    // bbox for tile t (float corner math, +/-1 margins; corners bound the
    // interior of an affine map)
    const int tileY = t / tilesX, tileX = t - tileY * tilesX;
    const int tx0 = tileX * TW, ty0 = tileY * TH;
    const int tx1 = min(tx0 + TW - 1, W - 1);
    const int ty1 = min(ty0 + TH - 1, H - 1);
    const float cx0 = (float)tx0 - f13, cx1 = (float)tx1 - f13;
    const float cy0 = (float)ty0 - f23, cy1 = (float)ty1 - f23;
    const float sxA = i00 * cx0 + i01 * cy0, sxB = i00 * cx1 + i01 * cy0;
    const float sxC = i00 * cx0 + i01 * cy1, sxD = i00 * cx1 + i01 * cy1;
    const float syA = i10 * cx0 + i11 * cy0, syB = i10 * cx1 + i11 * cy0;
    const float syC = i10 * cx0 + i11 * cy1, syD = i10 * cx1 + i11 * cy1;
    const float sxmin = fminf(fminf(sxA, sxB), fminf(sxC, sxD));
    const float symin = fminf(fminf(syA, syB), fminf(syC, syD));
    const float symax = fmaxf(fmaxf(syA, syB), fmaxf(syC, syD));
    const int xs0 = ((int)floorf(sxmin) - 1) & ~3;     // 4-aligned down
    const int ys0 = (int)floorf(symin) - 1;
    const int ys1 = min((int)floorf(symax) + 2, ys0 + MAXROWS - 1);
    int4 v; v.x = xs0; v.y = ys0; v.z = ys1 - ys0 + 1; v.w = 0;
    bb[idx] = v;
}

// Grid: (B, nTile, C). Block: 256 threads.
__global__ __launch_bounds__(256) void TCR_warp_kernel(
        const float* __restrict__ img, const float* __restrict__ p,
        const int4* __restrict__ bb, float* __restrict__ out,
        int H, int W, int tilesXShift) {
    __shared__ float lds[MAXROWS * PITCH + 4];

    const int tid = (int)threadIdx.x;
    const int b = (int)blockIdx.x;
    const int t = (int)blockIdx.y;
    const int c = (int)blockIdx.z;
    const int nTile = (int)gridDim.y;
    const int tileY = t >> tilesXShift;
    const int tileX = t - (tileY << tilesXShift);
    const int tx0 = tileX * TW, ty0 = tileY * TH;

    const int4 box = bb[b * nTile + t];
    const int xs0 = box.x, ys0 = box.y, hs = box.z;

    const float i00 = p[b * 6 + 0];
    const float i10 = p[b * 6 + 2];
    const float i11 = p[b * 6 + 3];
    const float T13 = p[b * 6 + 4];
    const float T23 = p[b * 6 + 5];

    const size_t plane = (size_t)H * W;
    const float* pl = img + ((size_t)b * 3 + c) * plane;

    // --- stage rows [ys0, ys0+hs) x cols [xs0, xs0+40) with zero-halo.
    // One ds_write_b128 per slot (o = ry*64 + 4*rp is 16B-aligned).
    const int nTask = hs * SLOTS;
    const bool fast = (xs0 >= 0) & (xs0 + 4 * SLOTS <= W) &
                      (ys0 >= 0) & (ys0 + hs <= H);
    if (fast) {
        for (int j = tid; j < nTask; j += 256) {
            const int ry = (int)((unsigned)j / SLOTS);   // literal -> magic mul
            const int rp = j - ry * SLOTS;
            const float4 f =
                *(const float4*)(pl + (size_t)(ys0 + ry) * W + xs0 + 4 * rp);
            *(float4*)&lds[(ry << 6) + 4 * rp] = f;
        }
    } else {
        for (int j = tid; j < nTask; j += 256) {
            const int ry = (int)((unsigned)j / SLOTS);
            const int rp = j - ry * SLOTS;
            const int gy = ys0 + ry;
            const int gx = xs0 + 4 * rp;
            const int gyc = min(max(gy, 0), H - 1);
            const int gxc = min(max(gx, 0), W - 4);
            float4 f = *(const float4*)(pl + (size_t)gyc * W + gxc);
            // whole-slot validity: xs0 and W are multiples of 4, so a slot is
            // fully inside or fully outside in x.
            const bool ok = ((unsigned)gy < (unsigned)H) &
                            ((unsigned)gx < (unsigned)W);
            f.x = ok ? f.x : 0.0f;
            f.y = ok ? f.y : 0.0f;
            f.z = ok ? f.z : 0.0f;
            f.w = ok ? f.w : 0.0f;
            *(float4*)&lds[(ry << 6) + 4 * rp] = f;
        }
    }
    __syncthreads();

    // --- compute: thread (xl = tid&31, yl = tid>>5), 4 y-steps of stride 8.
    const int xl = tid & 31;
    const int yl = tid >> 5;
    const int x = tx0 + xl;
    const int ybase = ty0 + yl;

    const float dx = (float)x - T13;
    // i01 == 0 exactly (a = hx - r = 0): sx is y-invariant -> hoist x-path.
    const float sxl = i00 * dx - (float)xs0;
    const float x0f = floorf(sxl);
    const float wx = sxl - x0f;
    const int x0 = (int)x0f;

    float syl = i10 * dx + i11 * ((float)ybase - T23) - (float)ys0;
    const float dsy = 8.0f * i11;

    float* po = out + ((size_t)b * 3 + c) * plane + (size_t)ybase * W + x;

    if ((tx0 + TW <= W) & (ty0 + TH <= H)) {   // full tile (always, here)
        #pragma unroll
        for (int k = 0; k < TH / 8; ++k) {
            const float y0f = floorf(syl);
            const float wy = syl - y0f;
            const int y0 = (int)y0f;
            const int iA = (y0 << 6) + x0;
            const float v00 = lds[iA];
            const float v01 = lds[iA + 1];
            const float v10 = lds[iA + PITCH];
            const float v11 = lds[iA + PITCH + 1];
            const float top = v00 + wx * (v01 - v00);
            const float bot = v10 + wx * (v11 - v10);
            *po = top + wy * (bot - top);
            po  += 8 * W;
            syl += dsy;
        }
    } else {                                   // partial tile (generality)
        if (x >= W) return;
        #pragma unroll
        for (int k = 0; k < TH / 8; ++k) {
            const int y = ybase + 8 * k;
            if (y >= H) break;
            const float y0f = floorf(syl);
            const float wy = syl - y0f;
            const int y0 = (int)y0f;
            const int iA = (y0 << 6) + x0;
            const float v00 = lds[iA];
            const float v01 = lds[iA + 1];
            const float v10 = lds[iA + PITCH];
            const float v11 = lds[iA + PITCH + 1];
            const float top = v00 + wx * (v01 - v00);
            const float bot = v10 + wx * (v11 - v10);
            *po = top + wy * (bot - top);
            po  += 8 * W;
            syl += dsy;
        }
    }
}

extern "C" void kernel_launch(void* const* d_in, const int* in_sizes, int n_in,
                              void* d_out, int out_size, void* d_ws, size_t ws_size,
                              hipStream_t stream) {
    const float* img = (const float*)d_in[0];
    const float* rnd = (const float*)d_in[1];
    float* out = (float*)d_out;
    float* params = (float*)d_ws;

    const int B = in_sizes[1];            // 128
    const int C = 3;
    const int total = in_sizes[0];        // B*C*H*W
    const int HW = total / (B * C);       // 65536
    int W = 256;                          // square images
    while (W * W > HW) W >>= 1;
    const int H = HW / W;

    const int tilesX = (W + TW - 1) / TW;     // 8 (pow2 for W=256)
    const int tilesY = (H + TH - 1) / TH;     // 8
    const int nTile = tilesX * tilesY;        // 64
    int tilesXShift = 0;
    while ((1 << tilesXShift) < tilesX) ++tilesXShift;

    // ws layout: params (B*6 floats) | bbox (B*nTile int4), 16B-aligned
    int4* bbox = (int4*)((char*)d_ws + ((B * 6 * sizeof(float) + 15) & ~15));

    const int nPar = B * nTile;
    TCR_params_kernel<<<(nPar + 255) / 256, 256, 0, stream>>>(
        rnd, params, bbox, B, W, H, tilesX, nTile);

    dim3 grid(B, nTile, C);
    TCR_warp_kernel<<<grid, 256, 0, stream>>>(img, params, bbox, out,
                                              H, W, tilesXShift);
}

// Round 11
// 37.941 us; speedup vs baseline: 1.0964x; 1.0964x over previous
//
#include <hip/hip_runtime.h>
#include <math.h>

// Affine warp augmentation (kornia-style warp_affine, bilinear, zeros padding,
// align_corners pixel coords). B=128, C=3, H=W=256, fp32.
//
// R11: SINGLE kernel. R8-R10 falsified every on-CU bottleneck (VALU, bank
// conflicts, NT stores, occupancy) with the bench pinned at ~41.5us: the warp
// kernel is write-stream bound (FETCH~0 in timed replays, WRITE=98.3MB
// compulsory, ~2.7 TB/s ~ 87% of the ~3.1 TB/s per-direction ceiling). The
// only slack left is the serial prologue: the old params kernel ran 8192
// threads of chained fp64 trig (~2-4us latency) + a launch gap. Now each
// block computes its params in fp32 (__sincosf + double-angle; a = hx-r = 0
// EXACTLY since both are the same fp expression, so ca=1/sa=0 are exact) and
// its own bbox — ~100cy redundant VALU per thread, no extra barrier, no d_ws.
// fp32 param error ~1e-6 rel -> coord error ~5e-4 px -> output ~1e-3 << 0.02.
//
// Carried from R10: TW=32/TH=32, PITCH=64 (gather bank = x0%32, angle-
// independent ~conflict-free), MAXROWS=70 -> LDS 17.9KB -> 8 blocks/CU,
// float4 zero-halo staging (fast interior path), ds_write_b128 staging,
// i01==0 -> sx/x0/wx hoisted, 3D grid (B,nTile,C) -> no divides + implicit
// XCD pinning (gridDim.x=128 = 0 mod 8), mask-free bilinear inner loop.

#define TW 32
#define TH 32
#define PITCH 64       // power-of-2: bank = x0 % 32 (y0 vanishes); b128-aligned
#define MAXROWS 70     // >= (|i10|+i11)*31 + 5 = 62.5 + 5
#define SLOTS 10       // staged float4 slots per row (40 floats >= ws 38)

// Grid: (B, nTile, C). Block: 256 threads.
__global__ __launch_bounds__(256) void TCR_warp_kernel(
        const float* __restrict__ img, const float* __restrict__ rnd,
        float* __restrict__ out, int H, int W, int tilesXShift) {
    __shared__ float lds[MAXROWS * PITCH + 4];

    const int tid = (int)threadIdx.x;
    const int b = (int)blockIdx.x;
    const int t = (int)blockIdx.y;
    const int c = (int)blockIdx.z;
    const int tileY = t >> tilesXShift;
    const int tileX = t - (tileY << tilesXShift);
    const int tx0 = tileX * TW, ty0 = tileY * TH;

    // ---- per-block affine params, fp32 (uniform across threads) ----
    const float r01 = rnd[b];
    const float txs = 12.0f * r01 - 6.0f;          // tx = ty (same random)
    const float r   = 0.69813170079773180f * r01 - 0.34906585039886590f;
    float sr, cr;
    __sincosf(r, &sr, &cr);
    const float cb = cr * cr - sr * sr;            // cos 2r  (>= 0.766)
    const float sb = 2.0f * sr * cr;               // sin 2r
    const float rc = 1.0f / cr;
    const float WF = (float)W, HF = (float)H;
    // a = hx - r = 0 exactly -> ca=1, sa=0; z=1.
    const float T11 = rc;
    const float T13 = (WF * cr - WF + 2.0f * txs) * (0.5f * rc);
    const float T21 = sb * rc;
    const float T22 = cb * rc;
    const float T23 = (HF * cr - WF * cb + 2.0f * txs * cb
                       - WF * sb + 2.0f * txs * sb) * (0.5f * rc);
    const float rdet = 1.0f / (T11 * T22);         // T12 == 0
    const float i00 = T22 * rdet;                  // = cr
    const float i10 = -T21 * rdet;
    const float i11 = T11 * rdet;

    // ---- per-block source bbox (i01 == 0; corners bound the interior) ----
    const float cx0 = (float)tx0 - T13;
    const float cx1 = (float)(tx0 + TW - 1) - T13;
    const float cy0 = (float)ty0 - T23;
    const float cy1 = (float)(ty0 + TH - 1) - T23;
    const float sxmin = fminf(i00 * cx0, i00 * cx1);
    const float symin = fminf(i10 * cx0, i10 * cx1) + fminf(i11 * cy0, i11 * cy1);
    const float symax = fmaxf(i10 * cx0, i10 * cx1) + fmaxf(i11 * cy0, i11 * cy1);
    const int xs0 = (((int)floorf(sxmin)) - 1) & ~3;   // 4-aligned down
    const int ys0 = (int)floorf(symin) - 1;
    const int ys1 = min((int)floorf(symax) + 2, ys0 + MAXROWS - 1);
    const int hs = ys1 - ys0 + 1;

    const size_t plane = (size_t)H * W;
    const float* pl = img + ((size_t)b * 3 + c) * plane;

    // --- stage rows [ys0, ys0+hs) x cols [xs0, xs0+40) with zero-halo.
    // One ds_write_b128 per slot (o = ry*64 + 4*rp is 16B-aligned).
    const int nTask = hs * SLOTS;
    const bool fast = (xs0 >= 0) & (xs0 + 4 * SLOTS <= W) &
                      (ys0 >= 0) & (ys0 + hs <= H);
    if (fast) {
        for (int j = tid; j < nTask; j += 256) {
            const int ry = (int)((unsigned)j / SLOTS);   // literal -> magic mul
            const int rp = j - ry * SLOTS;
            const float4 f =
                *(const float4*)(pl + (size_t)(ys0 + ry) * W + xs0 + 4 * rp);
            *(float4*)&lds[(ry << 6) + 4 * rp] = f;
        }
    } else {
        for (int j = tid; j < nTask; j += 256) {
            const int ry = (int)((unsigned)j / SLOTS);
            const int rp = j - ry * SLOTS;
            const int gy = ys0 + ry;
            const int gx = xs0 + 4 * rp;
            const int gyc = min(max(gy, 0), H - 1);
            const int gxc = min(max(gx, 0), W - 4);
            float4 f = *(const float4*)(pl + (size_t)gyc * W + gxc);
            // whole-slot validity: xs0 and W are multiples of 4, so a slot is
            // fully inside or fully outside in x.
            const bool ok = ((unsigned)gy < (unsigned)H) &
                            ((unsigned)gx < (unsigned)W);
            f.x = ok ? f.x : 0.0f;
            f.y = ok ? f.y : 0.0f;
            f.z = ok ? f.z : 0.0f;
            f.w = ok ? f.w : 0.0f;
            *(float4*)&lds[(ry << 6) + 4 * rp] = f;
        }
    }
    __syncthreads();

    // --- compute: thread (xl = tid&31, yl = tid>>5), 4 y-steps of stride 8.
    const int xl = tid & 31;
    const int yl = tid >> 5;
    const int x = tx0 + xl;
    const int ybase = ty0 + yl;

    const float dx = (float)x - T13;
    // i01 == 0 exactly: sx is y-invariant -> hoist x-path out of the loop.
    const float sxl = i00 * dx - (float)xs0;
    const float x0f = floorf(sxl);
    const float wx = sxl - x0f;
    const int x0 = (int)x0f;

    float syl = i10 * dx + i11 * ((float)ybase - T23) - (float)ys0;
    const float dsy = 8.0f * i11;

    float* po = out + ((size_t)b * 3 + c) * plane + (size_t)ybase * W + x;

    if ((tx0 + TW <= W) & (ty0 + TH <= H)) {   // full tile (always, here)
        #pragma unroll
        for (int k = 0; k < TH / 8; ++k) {
            const float y0f = floorf(syl);
            const float wy = syl - y0f;
            const int y0 = (int)y0f;
            const int iA = (y0 << 6) + x0;
            const float v00 = lds[iA];
            const float v01 = lds[iA + 1];
            const float v10 = lds[iA + PITCH];
            const float v11 = lds[iA + PITCH + 1];
            const float top = v00 + wx * (v01 - v00);
            const float bot = v10 + wx * (v11 - v10);
            *po = top + wy * (bot - top);
            po  += 8 * W;
            syl += dsy;
        }
    } else {                                   // partial tile (generality)
        if (x >= W) return;
        #pragma unroll
        for (int k = 0; k < TH / 8; ++k) {
            const int y = ybase + 8 * k;
            if (y >= H) break;
            const float y0f = floorf(syl);
            const float wy = syl - y0f;
            const int y0 = (int)y0f;
            const int iA = (y0 << 6) + x0;
            const float v00 = lds[iA];
            const float v01 = lds[iA + 1];
            const float v10 = lds[iA + PITCH];
            const float v11 = lds[iA + PITCH + 1];
            const float top = v00 + wx * (v01 - v00);
            const float bot = v10 + wx * (v11 - v10);
            *po = top + wy * (bot - top);
            po  += 8 * W;
            syl += dsy;
        }
    }
}

extern "C" void kernel_launch(void* const* d_in, const int* in_sizes, int n_in,
                              void* d_out, int out_size, void* d_ws, size_t ws_size,
                              hipStream_t stream) {
    const float* img = (const float*)d_in[0];
    const float* rnd = (const float*)d_in[1];
    float* out = (float*)d_out;
    (void)d_ws; (void)ws_size;

    const int B = in_sizes[1];            // 128
    const int C = 3;
    const int total = in_sizes[0];        // B*C*H*W
    const int HW = total / (B * C);       // 65536
    int W = 256;                          // square images
    while (W * W > HW) W >>= 1;
    const int H = HW / W;

    const int tilesX = (W + TW - 1) / TW;     // 8 (pow2 for W=256)
    const int tilesY = (H + TH - 1) / TH;     // 8
    const int nTile = tilesX * tilesY;        // 64
    int tilesXShift = 0;
    while ((1 << tilesXShift) < tilesX) ++tilesXShift;

    dim3 grid(B, nTile, C);
    TCR_warp_kernel<<<grid, 256, 0, stream>>>(img, rnd, out, H, W, tilesXShift);
}